// Round 1
// baseline (1538.469 us; speedup 1.0000x reference)
//
#include <hip/hip_runtime.h>
#include <stdint.h>

#define B_ 4
#define H_ 16
#define S_ 2048
#define D_ 64
#define QBLK 16
#define NTHREADS 512
#define ESTRIDE (S_ + 8)   /* shorts; +8 pad to break bank conflicts on b128 reads */
#define QSTRIDE (D_ + 8)

typedef __attribute__((ext_vector_type(8))) short short8;
typedef __attribute__((ext_vector_type(4))) short short4v;
typedef __attribute__((ext_vector_type(4))) float float4v;

static __device__ __forceinline__ short f2bf(float f) {
  uint32_t u = __builtin_bit_cast(uint32_t, f);
  u = (u + 0x7FFFu + ((u >> 16) & 1u)) >> 16;   // RNE
  return (short)u;
}
static __device__ __forceinline__ float bf2f(short s) {
  uint32_t u = ((uint32_t)(uint16_t)s) << 16;
  return __builtin_bit_cast(float, u);
}

// LDS layout (bytes)
#define EBUF_BYTES (QBLK * ESTRIDE * 2)            // 65792
#define QBUF_OFF   EBUF_BYTES
#define QBUF_BYTES (QBLK * QSTRIDE * 2)            // 2304
#define CBUF_OFF   (QBUF_OFF + QBUF_BYTES)
#define CBUF_BYTES (QBLK * D_ * 4)                 // 4096
#define LSUM_OFF   (CBUF_OFF + CBUF_BYTES)
#define LINV_OFF   (LSUM_OFF + QBLK * 4)
#define SMEM_BYTES (LINV_OFF + QBLK * 4)           // 72320

// Probe mask dtype: bit0 = nonzero byte at i%4!=0, bit1 = nonzero byte at i%4==0.
// uint8/bool -> (1,1); int32 0/1 LE -> (0,1); float32 0.0/1.0 -> (1,0).
__global__ void detect_mask_dtype(const uint8_t* __restrict__ m, uint32_t* flag) {
  uint32_t a = 0, b = 0;
  for (int i = threadIdx.x; i < 65536; i += 256) {
    uint8_t x = m[i];
    if (i & 3) a |= x; else b |= x;
  }
  uint32_t bits = (a ? 1u : 0u) | (b ? 2u : 0u);
  if (bits) atomicOr(flag, bits);
}

__global__ __launch_bounds__(NTHREADS, 4) void attn_fused(
    const float* __restrict__ Q, const float* __restrict__ K,
    const float* __restrict__ V, const float* __restrict__ scale_p,
    const uint8_t* __restrict__ M, const uint32_t* __restrict__ flag,
    float* __restrict__ outC, float* __restrict__ outA)
{
  extern __shared__ char smem[];
  short* ebuf = (short*)smem;                   // [QBLK][ESTRIDE] bf16, unnormalized exp
  short* qbuf = (short*)(smem + QBUF_OFF);      // [QBLK][QSTRIDE] bf16 Q tile
  float* cbuf = (float*)(smem + CBUF_OFF);      // [QBLK][D_] fp32 context partials
  float* lsum = (float*)(smem + LSUM_OFF);      // [QBLK] row sums
  float* linv = (float*)(smem + LINV_OFF);      // [QBLK] 1/rowsum

  const int bx  = blockIdx.x;
  const int bh  = bx >> 7;                      // 128 q-tiles per (b,h)
  const int q0  = (bx & 127) * QBLK;

  const int tid  = threadIdx.x;
  const int w    = tid >> 6;
  const int lane = tid & 63;
  const int g    = lane >> 4;                   // 0..3
  const int c    = lane & 15;                   // 0..15

  const float scale = scale_p[0];
  const uint32_t fl = flag[0];
  size_t mstride; int moff;
  if ((fl & 1u) && (fl & 2u)) { mstride = 1; moff = 0; }   // uint8/bool
  else if (!(fl & 1u))        { mstride = 4; moff = 0; }   // int32 LE
  else                        { mstride = 4; moff = 3; }   // float32
  const uint8_t* mbase = M + ((size_t)bh * S_ + q0) * (size_t)S_ * mstride + moff;

  const float* Qp = Q + ((size_t)bh * S_ + q0) * D_;
  const float* Kp = K + (size_t)bh * S_ * D_;
  const float* Vp = V + (size_t)bh * S_ * D_;

  for (int i = tid; i < QBLK * D_; i += NTHREADS) {
    int r = i >> 6, d = i & 63;
    qbuf[r * QSTRIDE + d] = f2bf(Qp[(size_t)r * D_ + d]);
    cbuf[i] = 0.0f;
  }
  if (tid < QBLK) lsum[tid] = 0.0f;
  __syncthreads();

  // Q A-frags (row = c, kdim d = h*32 + g*8 + e), loaded once
  short8 qA[2];
#pragma unroll
  for (int h = 0; h < 2; ++h)
    qA[h] = *(const short8*)&qbuf[c * QSTRIDE + h * 32 + g * 8];

  const int kbase = w * (S_ / 8);               // 256-wide private k-slab per wave
  float rsv[4] = {0.f, 0.f, 0.f, 0.f};
  float4v cacc[4];
#pragma unroll
  for (int nd = 0; nd < 4; ++nd) cacc[nd] = (float4v){0.f, 0.f, 0.f, 0.f};

  for (int kk = 0; kk < 8; ++kk) {
    const int k0 = kbase + kk * 32;

    // K B-frags: col = k0+16n+c, kdim d = h*32+g*8+e  -> K[col][d..d+7]
    short8 kB[2][2];
#pragma unroll
    for (int n = 0; n < 2; ++n) {
      const float* kr = Kp + (size_t)(k0 + n * 16 + c) * D_;
#pragma unroll
      for (int h = 0; h < 2; ++h) {
        float4v a = *(const float4v*)(kr + h * 32 + g * 8);
        float4v b = *(const float4v*)(kr + h * 32 + g * 8 + 4);
        short8 f;
        f[0]=f2bf(a.x); f[1]=f2bf(a.y); f[2]=f2bf(a.z); f[3]=f2bf(a.w);
        f[4]=f2bf(b.x); f[5]=f2bf(b.y); f[6]=f2bf(b.z); f[7]=f2bf(b.w);
        kB[n][h] = f;
      }
    }

    float4v acc0 = (float4v){0.f,0.f,0.f,0.f};
    float4v acc1 = (float4v){0.f,0.f,0.f,0.f};
    acc0 = __builtin_amdgcn_mfma_f32_16x16x32_bf16(qA[0], kB[0][0], acc0, 0, 0, 0);
    acc0 = __builtin_amdgcn_mfma_f32_16x16x32_bf16(qA[1], kB[0][1], acc0, 0, 0, 0);
    acc1 = __builtin_amdgcn_mfma_f32_16x16x32_bf16(qA[0], kB[1][0], acc1, 0, 0, 0);
    acc1 = __builtin_amdgcn_mfma_f32_16x16x32_bf16(qA[1], kB[1][1], acc1, 0, 0, 0);

    // mask + exp + row-sum + store E (D-frag: row q = g*4+r, col k = k0+16n+c)
#pragma unroll
    for (int n = 0; n < 2; ++n) {
      const float4v accv = n ? acc1 : acc0;
      const int kc = k0 + n * 16 + c;
#pragma unroll
      for (int r = 0; r < 4; ++r) {
        const int qr = g * 4 + r;
        uint8_t mb = mbase[((size_t)qr * S_ + kc) * mstride];
        float e = mb ? 1.0f : __expf(accv[r] * scale);  // exp(1e-9)==1.0f
        rsv[r] += e;
        ebuf[qr * ESTRIDE + kc] = f2bf(e);
      }
    }

    // PV: A = E (row q=c, kdim k = k0+g*8+e), B = V (col d=16nd+c, same kdim)
    short8 eA = *(const short8*)&ebuf[c * ESTRIDE + k0 + g * 8];
#pragma unroll
    for (int nd = 0; nd < 4; ++nd) {
      const float* vc = Vp + (size_t)(k0 + g * 8) * D_ + nd * 16 + c;
      short8 vB;
#pragma unroll
      for (int e = 0; e < 8; ++e) vB[e] = f2bf(vc[(size_t)e * D_]);
      cacc[nd] = __builtin_amdgcn_mfma_f32_16x16x32_bf16(eA, vB, cacc[nd], 0, 0, 0);
    }
  }

  // row-sum reduce across the 16 column-lanes (bits 0..3 of lane)
#pragma unroll
  for (int r = 0; r < 4; ++r) {
#pragma unroll
    for (int b = 1; b < 16; b <<= 1)
      rsv[r] += __shfl_xor(rsv[r], b, 64);
  }
  if (c == 0) {
#pragma unroll
    for (int r = 0; r < 4; ++r) atomicAdd(&lsum[g * 4 + r], rsv[r]);
  }
  // context partial reduce (8 waves own disjoint k-slabs -> sum)
#pragma unroll
  for (int nd = 0; nd < 4; ++nd)
#pragma unroll
    for (int r = 0; r < 4; ++r)
      atomicAdd(&cbuf[(g * 4 + r) * D_ + nd * 16 + c], cacc[nd][r]);
  __syncthreads();

  if (tid < QBLK) linv[tid] = 1.0f / lsum[tid];
  __syncthreads();

  // context write: 16 rows x 64 d
  if (tid < QBLK * D_ / 4) {
    int r = tid >> 4, d0 = (tid & 15) * 4;
    float inv = linv[r];
    float4v cv;
    cv.x = cbuf[r * D_ + d0 + 0] * inv;
    cv.y = cbuf[r * D_ + d0 + 1] * inv;
    cv.z = cbuf[r * D_ + d0 + 2] * inv;
    cv.w = cbuf[r * D_ + d0 + 3] * inv;
    *(float4v*)&outC[((size_t)bh * S_ + q0 + r) * D_ + d0] = cv;
  }

  // attention write: normalized, coalesced float4 per row
  float* arow = outA + ((size_t)bh * S_ + q0) * (size_t)S_;
#pragma unroll 1
  for (int r = 0; r < QBLK; ++r) {
    float inv = linv[r];
    short4v ev = *(const short4v*)&ebuf[r * ESTRIDE + tid * 4];
    float4v av;
    av.x = bf2f(ev[0]) * inv;
    av.y = bf2f(ev[1]) * inv;
    av.z = bf2f(ev[2]) * inv;
    av.w = bf2f(ev[3]) * inv;
    *(float4v*)&arow[(size_t)r * S_ + tid * 4] = av;
  }
}

extern "C" void kernel_launch(void* const* d_in, const int* in_sizes, int n_in,
                              void* d_out, int out_size, void* d_ws, size_t ws_size,
                              hipStream_t stream) {
  const float*   Q     = (const float*)d_in[0];
  const float*   K     = (const float*)d_in[1];
  const float*   V     = (const float*)d_in[2];
  const float*   scale = (const float*)d_in[3];
  const uint8_t* M     = (const uint8_t*)d_in[4];
  uint32_t* flag = (uint32_t*)d_ws;
  float* outC = (float*)d_out;
  float* outA = outC + (size_t)B_ * H_ * S_ * D_;

  hipMemsetAsync(flag, 0, 4, stream);
  detect_mask_dtype<<<dim3(1), dim3(256), 0, stream>>>(M, flag);

  hipFuncSetAttribute(reinterpret_cast<const void*>(attn_fused),
                      hipFuncAttributeMaxDynamicSharedMemorySize, SMEM_BYTES);
  attn_fused<<<dim3(B_ * H_ * (S_ / QBLK)), dim3(NTHREADS), SMEM_BYTES, stream>>>(
      Q, K, V, scale, M, flag, outC, outA);
}

// Round 2
// 1504.272 us; speedup vs baseline: 1.0227x; 1.0227x over previous
//
#include <hip/hip_runtime.h>
#include <stdint.h>

#define B_ 4
#define H_ 16
#define S_ 2048
#define D_ 64
#define QBLK 16
#define NTHREADS 1024
#define NWAVES (NTHREADS / 64)
#define KSLAB (S_ / NWAVES)          /* 128 */
#define KITER (KSLAB / 32)           /* 4 */
#define ESTRIDE (S_ + 8)             /* shorts */
#define QSTRIDE (D_ + 8)

typedef __attribute__((ext_vector_type(8))) short short8;
typedef __attribute__((ext_vector_type(4))) short short4v;
typedef __attribute__((ext_vector_type(4))) float float4v;

static __device__ __forceinline__ short f2bf(float f) {
  uint32_t u = __builtin_bit_cast(uint32_t, f);
  u = (u + 0x7FFFu + ((u >> 16) & 1u)) >> 16;   // RNE
  return (short)u;
}
static __device__ __forceinline__ float bf2f(short s) {
  uint32_t u = ((uint32_t)(uint16_t)s) << 16;
  return __builtin_bit_cast(float, u);
}

// LDS layout (bytes)
#define EBUF_BYTES (QBLK * ESTRIDE * 2)            // 65792
#define QBUF_OFF   EBUF_BYTES
#define QBUF_BYTES (QBLK * QSTRIDE * 2)
#define CBUF_OFF   (QBUF_OFF + QBUF_BYTES)
#define CBUF_BYTES (QBLK * D_ * 4)
#define LSUM_OFF   (CBUF_OFF + CBUF_BYTES)
#define LINV_OFF   (LSUM_OFF + QBLK * 4)
#define SMEM_BYTES (LINV_OFF + QBLK * 4)           // 72320

#define KBF_BYTES ((size_t)64 * S_ * D_ * 2)       // 16 MB
#define VT_BYTES  ((size_t)64 * S_ * D_ * 2)       // 16 MB

// Probe mask dtype: bit0 = nonzero byte at i%4!=0, bit1 = nonzero byte at i%4==0.
__global__ void detect_mask_dtype(const uint8_t* __restrict__ m, uint32_t* flag) {
  uint32_t a = 0, b = 0;
  for (int i = threadIdx.x; i < 65536; i += 256) {
    uint8_t x = m[i];
    if (i & 3) a |= x; else b |= x;
  }
  uint32_t bits = (a ? 1u : 0u) | (b ? 2u : 0u);
  if (bits) atomicOr(flag, bits);
}

// K fp32 [bh][k][d] -> bf16 same layout
__global__ __launch_bounds__(256) void prep_k(const float* __restrict__ K,
                                              short* __restrict__ Kbf) {
  size_t base = ((size_t)blockIdx.x * 256 + threadIdx.x) * 8;
  float4v a = *(const float4v*)(K + base);
  float4v b = *(const float4v*)(K + base + 4);
  short8 o;
  o[0]=f2bf(a.x); o[1]=f2bf(a.y); o[2]=f2bf(a.z); o[3]=f2bf(a.w);
  o[4]=f2bf(b.x); o[5]=f2bf(b.y); o[6]=f2bf(b.z); o[7]=f2bf(b.w);
  *(short8*)(Kbf + base) = o;
}

// V fp32 [bh][k][d] -> bf16 transposed [bh][d][k]
__global__ __launch_bounds__(256) void prep_vt(const float* __restrict__ V,
                                               short* __restrict__ VT) {
  __shared__ short tile[64][72];
  int bh = blockIdx.x >> 5, k0 = (blockIdx.x & 31) * 64;
  const float* src = V + ((size_t)bh * S_ + k0) * D_;
  int t = threadIdx.x;
  int r = t >> 2, c0 = (t & 3) * 16;
#pragma unroll
  for (int j = 0; j < 4; ++j) {
    float4v f = *(const float4v*)(src + (size_t)r * D_ + c0 + j * 4);
    tile[r][c0 + j*4 + 0] = f2bf(f.x);
    tile[r][c0 + j*4 + 1] = f2bf(f.y);
    tile[r][c0 + j*4 + 2] = f2bf(f.z);
    tile[r][c0 + j*4 + 3] = f2bf(f.w);
  }
  __syncthreads();
  int d = t >> 2, ks0 = (t & 3) * 16;
  short* dst = VT + (size_t)bh * D_ * S_ + (size_t)d * S_ + k0 + ks0;
#pragma unroll
  for (int half = 0; half < 2; ++half) {
    short8 o;
#pragma unroll
    for (int i = 0; i < 8; ++i) o[i] = tile[ks0 + half * 8 + i][d];
    *(short8*)(dst + half * 8) = o;
  }
}

template <int PREP>
__global__ __launch_bounds__(NTHREADS, 8) void attn_fused(
    const float* __restrict__ Q, const float* __restrict__ K,
    const float* __restrict__ V, const float* __restrict__ scale_p,
    const uint8_t* __restrict__ M, const uint32_t* __restrict__ flag,
    const short* __restrict__ Kbf, const short* __restrict__ VT,
    float* __restrict__ outC, float* __restrict__ outA)
{
  extern __shared__ char smem[];
  short* ebuf = (short*)smem;
  short* qbuf = (short*)(smem + QBUF_OFF);
  float* cbuf = (float*)(smem + CBUF_OFF);
  float* lsum = (float*)(smem + LSUM_OFF);
  float* linv = (float*)(smem + LINV_OFF);

  // XCD-chunked swizzle: hw block b -> work (b%8)*1024 + b/8 (8192 blocks)
  const int bx  = (blockIdx.x & 7) * 1024 + (blockIdx.x >> 3);
  const int bh  = bx >> 7;
  const int q0  = (bx & 127) * QBLK;

  const int tid  = threadIdx.x;
  const int w    = tid >> 6;
  const int lane = tid & 63;
  const int g    = lane >> 4;
  const int c    = lane & 15;

  const float scale = scale_p[0];
  const uint32_t fl = flag[0];
  size_t mstride; int moff;
  if ((fl & 1u) && (fl & 2u)) { mstride = 1; moff = 0; }
  else if (!(fl & 1u))        { mstride = 4; moff = 0; }
  else                        { mstride = 4; moff = 3; }
  const uint8_t* mbase = M + ((size_t)bh * S_ + q0) * (size_t)S_ * mstride + moff;

  const float* Qp = Q + ((size_t)bh * S_ + q0) * D_;
  const float* Kp = K + (size_t)bh * S_ * D_;
  const float* Vp = V + (size_t)bh * S_ * D_;
  const short* Kbp = PREP ? Kbf + (size_t)bh * S_ * D_ : nullptr;
  const short* VTp = PREP ? VT + (size_t)bh * D_ * S_ : nullptr;

  for (int i = tid; i < QBLK * D_; i += NTHREADS) {
    int r = i >> 6, d = i & 63;
    qbuf[r * QSTRIDE + d] = f2bf(Qp[(size_t)r * D_ + d]);
    cbuf[i] = 0.0f;
  }
  if (tid < QBLK) lsum[tid] = 0.0f;
  __syncthreads();

  short8 qA[2];
#pragma unroll
  for (int h = 0; h < 2; ++h)
    qA[h] = *(const short8*)&qbuf[c * QSTRIDE + h * 32 + g * 8];

  const int kbase = w * KSLAB;
  float rsv[4] = {0.f, 0.f, 0.f, 0.f};
  float4v cacc[4];
#pragma unroll
  for (int nd = 0; nd < 4; ++nd) cacc[nd] = (float4v){0.f, 0.f, 0.f, 0.f};

  for (int kk = 0; kk < KITER; ++kk) {
    const int k0 = kbase + kk * 32;

    short8 kB[2][2];
    if (PREP) {
#pragma unroll
      for (int n = 0; n < 2; ++n) {
        const short* kr = Kbp + (size_t)(k0 + n * 16 + c) * D_;
#pragma unroll
        for (int h = 0; h < 2; ++h)
          kB[n][h] = *(const short8*)(kr + h * 32 + g * 8);
      }
    } else {
#pragma unroll
      for (int n = 0; n < 2; ++n) {
        const float* kr = Kp + (size_t)(k0 + n * 16 + c) * D_;
#pragma unroll
        for (int h = 0; h < 2; ++h) {
          float4v a = *(const float4v*)(kr + h * 32 + g * 8);
          float4v b = *(const float4v*)(kr + h * 32 + g * 8 + 4);
          short8 f;
          f[0]=f2bf(a.x); f[1]=f2bf(a.y); f[2]=f2bf(a.z); f[3]=f2bf(a.w);
          f[4]=f2bf(b.x); f[5]=f2bf(b.y); f[6]=f2bf(b.z); f[7]=f2bf(b.w);
          kB[n][h] = f;
        }
      }
    }

    float4v acc0 = (float4v){0.f,0.f,0.f,0.f};
    float4v acc1 = (float4v){0.f,0.f,0.f,0.f};
    acc0 = __builtin_amdgcn_mfma_f32_16x16x32_bf16(qA[0], kB[0][0], acc0, 0, 0, 0);
    acc0 = __builtin_amdgcn_mfma_f32_16x16x32_bf16(qA[1], kB[0][1], acc0, 0, 0, 0);
    acc1 = __builtin_amdgcn_mfma_f32_16x16x32_bf16(qA[0], kB[1][0], acc1, 0, 0, 0);
    acc1 = __builtin_amdgcn_mfma_f32_16x16x32_bf16(qA[1], kB[1][1], acc1, 0, 0, 0);

#pragma unroll
    for (int n = 0; n < 2; ++n) {
      const float4v accv = n ? acc1 : acc0;
      const int kc = k0 + n * 16 + c;
#pragma unroll
      for (int r = 0; r < 4; ++r) {
        const int qr = g * 4 + r;
        uint8_t mb = mbase[((size_t)qr * S_ + kc) * mstride];
        float e = mb ? 1.0f : __expf(accv[r] * scale);
        rsv[r] += e;
        ebuf[qr * ESTRIDE + kc] = f2bf(e);
      }
    }

    short8 eA = *(const short8*)&ebuf[c * ESTRIDE + k0 + g * 8];
#pragma unroll
    for (int nd = 0; nd < 4; ++nd) {
      short8 vB;
      if (PREP) {
        vB = *(const short8*)&VTp[(size_t)(nd * 16 + c) * S_ + k0 + g * 8];
      } else {
        const float* vc = Vp + (size_t)(k0 + g * 8) * D_ + nd * 16 + c;
#pragma unroll
        for (int e = 0; e < 8; ++e) vB[e] = f2bf(vc[(size_t)e * D_]);
      }
      cacc[nd] = __builtin_amdgcn_mfma_f32_16x16x32_bf16(eA, vB, cacc[nd], 0, 0, 0);
    }
  }

#pragma unroll
  for (int r = 0; r < 4; ++r) {
#pragma unroll
    for (int b = 1; b < 16; b <<= 1)
      rsv[r] += __shfl_xor(rsv[r], b, 64);
  }
  if (c == 0) {
#pragma unroll
    for (int r = 0; r < 4; ++r) atomicAdd(&lsum[g * 4 + r], rsv[r]);
  }
#pragma unroll
  for (int nd = 0; nd < 4; ++nd)
#pragma unroll
    for (int r = 0; r < 4; ++r)
      atomicAdd(&cbuf[(g * 4 + r) * D_ + nd * 16 + c], cacc[nd][r]);
  __syncthreads();

  if (tid < QBLK) linv[tid] = 1.0f / lsum[tid];
  __syncthreads();

  if (tid < QBLK * D_ / 4) {
    int r = tid >> 4, d0 = (tid & 15) * 4;
    float inv = linv[r];
    float4v cv;
    cv.x = cbuf[r * D_ + d0 + 0] * inv;
    cv.y = cbuf[r * D_ + d0 + 1] * inv;
    cv.z = cbuf[r * D_ + d0 + 2] * inv;
    cv.w = cbuf[r * D_ + d0 + 3] * inv;
    *(float4v*)&outC[((size_t)bh * S_ + q0 + r) * D_ + d0] = cv;
  }

  float* arow = outA + ((size_t)bh * S_ + q0) * (size_t)S_;
#pragma unroll 1
  for (int i = tid; i < QBLK * (S_ / 4); i += NTHREADS) {
    int r = i >> 9, col4 = (i & 511) * 4;
    float inv = linv[r];
    short4v ev = *(const short4v*)&ebuf[r * ESTRIDE + col4];
    float4v av;
    av.x = bf2f(ev[0]) * inv;
    av.y = bf2f(ev[1]) * inv;
    av.z = bf2f(ev[2]) * inv;
    av.w = bf2f(ev[3]) * inv;
    *(float4v*)&arow[(size_t)r * S_ + col4] = av;
  }
}

extern "C" void kernel_launch(void* const* d_in, const int* in_sizes, int n_in,
                              void* d_out, int out_size, void* d_ws, size_t ws_size,
                              hipStream_t stream) {
  const float*   Q     = (const float*)d_in[0];
  const float*   K     = (const float*)d_in[1];
  const float*   V     = (const float*)d_in[2];
  const float*   scale = (const float*)d_in[3];
  const uint8_t* M     = (const uint8_t*)d_in[4];
  uint32_t* flag = (uint32_t*)d_ws;
  float* outC = (float*)d_out;
  float* outA = outC + (size_t)B_ * H_ * S_ * D_;

  hipMemsetAsync(flag, 0, 4, stream);
  detect_mask_dtype<<<dim3(1), dim3(256), 0, stream>>>(M, flag);

  const bool prep = ws_size >= (size_t)64 + KBF_BYTES + VT_BYTES;
  if (prep) {
    short* Kbf = (short*)((char*)d_ws + 64);
    short* VT  = (short*)((char*)d_ws + 64 + KBF_BYTES);
    prep_k<<<dim3((B_ * H_ * S_ * D_) / (256 * 8)), dim3(256), 0, stream>>>(K, Kbf);
    prep_vt<<<dim3(B_ * H_ * (S_ / 64)), dim3(256), 0, stream>>>(V, VT);
    hipFuncSetAttribute(reinterpret_cast<const void*>(attn_fused<1>),
                        hipFuncAttributeMaxDynamicSharedMemorySize, SMEM_BYTES);
    attn_fused<1><<<dim3(B_ * H_ * (S_ / QBLK)), dim3(NTHREADS), SMEM_BYTES, stream>>>(
        Q, K, V, scale, M, flag, Kbf, VT, outC, outA);
  } else {
    hipFuncSetAttribute(reinterpret_cast<const void*>(attn_fused<0>),
                        hipFuncAttributeMaxDynamicSharedMemorySize, SMEM_BYTES);
    attn_fused<0><<<dim3(B_ * H_ * (S_ / QBLK)), dim3(NTHREADS), SMEM_BYTES, stream>>>(
        Q, K, V, scale, M, flag, nullptr, nullptr, outC, outA);
  }
}

// Round 3
// 1485.733 us; speedup vs baseline: 1.0355x; 1.0125x over previous
//
#include <hip/hip_runtime.h>
#include <stdint.h>

#define B_ 4
#define H_ 16
#define S_ 2048
#define D_ 64
#define QBLK 16
#define NTHREADS 1024
#define NWAVES 16
#define KSLAB (S_ / NWAVES)          /* 128 */
#define KITER (KSLAB / 32)           /* 4 */
#define ESTRIDE (S_ + 8)             /* shorts */
#define QSTRIDE (D_ + 8)

typedef __attribute__((ext_vector_type(8))) short short8;
typedef __attribute__((ext_vector_type(4))) short short4v;
typedef __attribute__((ext_vector_type(4))) float float4v;
typedef __attribute__((ext_vector_type(4))) unsigned int uint4v;

static __device__ __forceinline__ short f2bf(float f) {
  uint32_t u = __builtin_bit_cast(uint32_t, f);
  u = (u + 0x7FFFu + ((u >> 16) & 1u)) >> 16;   // RNE
  return (short)u;
}
static __device__ __forceinline__ float bf2f(short s) {
  uint32_t u = ((uint32_t)(uint16_t)s) << 16;
  return __builtin_bit_cast(float, u);
}
// nonzero-byte indicator: bits at 0,8,16,24
static __device__ __forceinline__ uint32_t nz4(uint32_t d) {
  uint32_t x = (d & 0x7F7F7F7Fu) + 0x7F7F7F7Fu;
  x = (x | d) & 0x80808080u;
  return x >> 7;
}
// nibble: bit j = (byte j of d != 0)
static __device__ __forceinline__ uint32_t nib(uint32_t d) {
  return ((nz4(d) * 0x01020408u) >> 24) & 0xFu;
}

// LDS layout (bytes)
#define EBUF_BYTES (QBLK * ESTRIDE * 2)            // 65792
#define QBUF_OFF   EBUF_BYTES
#define QBUF_BYTES (QBLK * QSTRIDE * 2)
#define CBUF_OFF   (QBUF_OFF + QBUF_BYTES)
#define CBUF_BYTES (QBLK * D_ * 4)
#define LSUM_OFF   (CBUF_OFF + CBUF_BYTES)
#define LINV_OFF   (LSUM_OFF + QBLK * 4)
#define MBITS_OFF  (LINV_OFF + QBLK * 4)
#define MBITS_BYTES (QBLK * 64 * 4)                // 4096 (16 rows x 2048 bits)
#define SMEM_BYTES (MBITS_OFF + MBITS_BYTES)       // 76416 -> 2 blocks/CU

#define KBF_BYTES ((size_t)64 * S_ * D_ * 2)       // 16 MB
#define VT_BYTES  ((size_t)64 * S_ * D_ * 2)       // 16 MB

// Probe mask dtype: bit0 = nonzero byte at i%4!=0, bit1 = nonzero byte at i%4==0.
// uint8/bool -> 3; int32 -> 2; float32 -> 1.
__global__ void detect_mask_dtype(const uint8_t* __restrict__ m, uint32_t* flag) {
  uint32_t a = 0, b = 0;
  for (int i = threadIdx.x; i < 65536; i += 256) {
    uint8_t x = m[i];
    if (i & 3) a |= x; else b |= x;
  }
  uint32_t bits = (a ? 1u : 0u) | (b ? 2u : 0u);
  if (bits) atomicOr(flag, bits);
}

// K fp32 [bh][k][d] -> bf16 same layout
__global__ __launch_bounds__(256) void prep_k(const float* __restrict__ K,
                                              short* __restrict__ Kbf) {
  size_t base = ((size_t)blockIdx.x * 256 + threadIdx.x) * 8;
  float4v a = __builtin_nontemporal_load((const float4v*)(K + base));
  float4v b = __builtin_nontemporal_load((const float4v*)(K + base + 4));
  short8 o;
  o[0]=f2bf(a.x); o[1]=f2bf(a.y); o[2]=f2bf(a.z); o[3]=f2bf(a.w);
  o[4]=f2bf(b.x); o[5]=f2bf(b.y); o[6]=f2bf(b.z); o[7]=f2bf(b.w);
  *(short8*)(Kbf + base) = o;
}

// V fp32 [bh][k][d] -> bf16 transposed [bh][d][k]
__global__ __launch_bounds__(256) void prep_vt(const float* __restrict__ V,
                                               short* __restrict__ VT) {
  __shared__ short tile[64][72];
  int bh = blockIdx.x >> 5, k0 = (blockIdx.x & 31) * 64;
  const float* src = V + ((size_t)bh * S_ + k0) * D_;
  int t = threadIdx.x;
  int r = t >> 2, c0 = (t & 3) * 16;
#pragma unroll
  for (int j = 0; j < 4; ++j) {
    float4v f = __builtin_nontemporal_load((const float4v*)(src + (size_t)r * D_ + c0 + j * 4));
    tile[r][c0 + j*4 + 0] = f2bf(f.x);
    tile[r][c0 + j*4 + 1] = f2bf(f.y);
    tile[r][c0 + j*4 + 2] = f2bf(f.z);
    tile[r][c0 + j*4 + 3] = f2bf(f.w);
  }
  __syncthreads();
  int d = t >> 2, ks0 = (t & 3) * 16;
  short* dst = VT + (size_t)bh * D_ * S_ + (size_t)d * S_ + k0 + ks0;
#pragma unroll
  for (int half = 0; half < 2; ++half) {
    short8 o;
#pragma unroll
    for (int i = 0; i < 8; ++i) o[i] = tile[ks0 + half * 8 + i][d];
    *(short8*)(dst + half * 8) = o;
  }
}

template <int PREP>
__global__ __launch_bounds__(NTHREADS, 8) void attn_fused(
    const float* __restrict__ Q, const float* __restrict__ K,
    const float* __restrict__ V, const float* __restrict__ scale_p,
    const uint8_t* __restrict__ M, const uint32_t* __restrict__ flag,
    const short* __restrict__ Kbf, const short* __restrict__ VT,
    float* __restrict__ outC, float* __restrict__ outA)
{
  extern __shared__ char smem[];
  short* ebuf = (short*)smem;
  short* qbuf = (short*)(smem + QBUF_OFF);
  float* cbuf = (float*)(smem + CBUF_OFF);
  float* lsum = (float*)(smem + LSUM_OFF);
  float* linv = (float*)(smem + LINV_OFF);
  uint32_t* mbits = (uint32_t*)(smem + MBITS_OFF);  // [QBLK][64] dwords

  // XCD-chunked swizzle: hw block b -> work (b%8)*1024 + b/8 (8192 blocks)
  const int bx  = (blockIdx.x & 7) * 1024 + (blockIdx.x >> 3);
  const int bh  = bx >> 7;
  const int q0  = (bx & 127) * QBLK;

  const int tid  = threadIdx.x;
  const int w    = tid >> 6;
  const int lane = tid & 63;
  const int g    = lane >> 4;
  const int c    = lane & 15;

  const float scale = scale_p[0];
  const uint32_t fl = flag[0];

  const float* Qp = Q + ((size_t)bh * S_ + q0) * D_;
  const float* Kp = K + (size_t)bh * S_ * D_;
  const float* Vp = V + (size_t)bh * S_ * D_;
  const short* Kbp = PREP ? Kbf + (size_t)bh * S_ * D_ : nullptr;
  const short* VTp = PREP ? VT + (size_t)bh * D_ * S_ : nullptr;

  // ---- mask prepass: pack block's [16][2048] mask slab to 4KB LDS bitmap ----
  {
    const int r = tid >> 6;          // 0..15
    const int wrd0 = tid & 63;       // word index 0..63 (32 bits each)
    uint32_t bits = 0;
    if (fl == 3u) {                  // uint8/bool mask
      const uint8_t* mrow = M + ((size_t)bh * S_ + q0 + r) * (size_t)S_ + wrd0 * 32;
      uint4v a = __builtin_nontemporal_load((const uint4v*)mrow);
      uint4v b = __builtin_nontemporal_load((const uint4v*)(mrow + 16));
      bits  = nib(a.x) | (nib(a.y) << 4) | (nib(a.z) << 8)  | (nib(a.w) << 12)
            | (nib(b.x) << 16) | (nib(b.y) << 20) | (nib(b.z) << 24) | (nib(b.w) << 28);
    } else {                         // 4-byte mask (int32 or float32): nonzero dword
      const uint32_t* mrow = (const uint32_t*)M + ((size_t)bh * S_ + q0 + r) * (size_t)S_ + wrd0 * 32;
#pragma unroll
      for (int j = 0; j < 8; ++j) {
        uint4v wv = __builtin_nontemporal_load((const uint4v*)(mrow + j * 4));
        uint32_t nzb = (wv.x ? 1u : 0u) | (wv.y ? 2u : 0u) | (wv.z ? 4u : 0u) | (wv.w ? 8u : 0u);
        bits |= nzb << (j * 4);
      }
    }
    mbits[r * 64 + wrd0] = bits;
  }

  for (int i = tid; i < QBLK * D_; i += NTHREADS) {
    int r = i >> 6, d = i & 63;
    qbuf[r * QSTRIDE + d] = f2bf(Qp[(size_t)r * D_ + d]);
    cbuf[i] = 0.0f;
  }
  if (tid < QBLK) lsum[tid] = 0.0f;
  __syncthreads();

  short8 qA[2];
#pragma unroll
  for (int h = 0; h < 2; ++h)
    qA[h] = *(const short8*)&qbuf[c * QSTRIDE + h * 32 + g * 8];

  const int kbase = w * KSLAB;
  float rsv[4] = {0.f, 0.f, 0.f, 0.f};
  float4v cacc[4];
#pragma unroll
  for (int nd = 0; nd < 4; ++nd) cacc[nd] = (float4v){0.f, 0.f, 0.f, 0.f};

  for (int kk = 0; kk < KITER; ++kk) {
    const int k0 = kbase + kk * 32;

    short8 kB[2][2];
    if (PREP) {
#pragma unroll
      for (int n = 0; n < 2; ++n) {
        const short* kr = Kbp + (size_t)(k0 + n * 16 + c) * D_;
#pragma unroll
        for (int h = 0; h < 2; ++h)
          kB[n][h] = *(const short8*)(kr + h * 32 + g * 8);
      }
    } else {
#pragma unroll
      for (int n = 0; n < 2; ++n) {
        const float* kr = Kp + (size_t)(k0 + n * 16 + c) * D_;
#pragma unroll
        for (int h = 0; h < 2; ++h) {
          float4v a = *(const float4v*)(kr + h * 32 + g * 8);
          float4v b = *(const float4v*)(kr + h * 32 + g * 8 + 4);
          short8 f;
          f[0]=f2bf(a.x); f[1]=f2bf(a.y); f[2]=f2bf(a.z); f[3]=f2bf(a.w);
          f[4]=f2bf(b.x); f[5]=f2bf(b.y); f[6]=f2bf(b.z); f[7]=f2bf(b.w);
          kB[n][h] = f;
        }
      }
    }

    // mask words for this kk: word index = w*4 + kk, rows g*4+r (broadcast reads)
    uint32_t mw[4];
#pragma unroll
    for (int r = 0; r < 4; ++r)
      mw[r] = mbits[(g * 4 + r) * 64 + w * 4 + kk];

    float4v acc0 = (float4v){0.f,0.f,0.f,0.f};
    float4v acc1 = (float4v){0.f,0.f,0.f,0.f};
    acc0 = __builtin_amdgcn_mfma_f32_16x16x32_bf16(qA[0], kB[0][0], acc0, 0, 0, 0);
    acc0 = __builtin_amdgcn_mfma_f32_16x16x32_bf16(qA[1], kB[0][1], acc0, 0, 0, 0);
    acc1 = __builtin_amdgcn_mfma_f32_16x16x32_bf16(qA[0], kB[1][0], acc1, 0, 0, 0);
    acc1 = __builtin_amdgcn_mfma_f32_16x16x32_bf16(qA[1], kB[1][1], acc1, 0, 0, 0);

#pragma unroll
    for (int n = 0; n < 2; ++n) {
      const float4v accv = n ? acc1 : acc0;
      const int kc = k0 + n * 16 + c;
#pragma unroll
      for (int r = 0; r < 4; ++r) {
        const int qr = g * 4 + r;
        const uint32_t masked = (mw[r] >> (n * 16 + c)) & 1u;
        float e = masked ? 1.0f : __expf(accv[r] * scale);
        rsv[r] += e;
        ebuf[qr * ESTRIDE + kc] = f2bf(e);
      }
    }

    short8 eA = *(const short8*)&ebuf[c * ESTRIDE + k0 + g * 8];
#pragma unroll
    for (int nd = 0; nd < 4; ++nd) {
      short8 vB;
      if (PREP) {
        vB = *(const short8*)&VTp[(size_t)(nd * 16 + c) * S_ + k0 + g * 8];
      } else {
        const float* vc = Vp + (size_t)(k0 + g * 8) * D_ + nd * 16 + c;
#pragma unroll
        for (int e = 0; e < 8; ++e) vB[e] = f2bf(vc[(size_t)e * D_]);
      }
      cacc[nd] = __builtin_amdgcn_mfma_f32_16x16x32_bf16(eA, vB, cacc[nd], 0, 0, 0);
    }
  }

#pragma unroll
  for (int r = 0; r < 4; ++r) {
#pragma unroll
    for (int b = 1; b < 16; b <<= 1)
      rsv[r] += __shfl_xor(rsv[r], b, 64);
  }
  if (c == 0) {
#pragma unroll
    for (int r = 0; r < 4; ++r) atomicAdd(&lsum[g * 4 + r], rsv[r]);
  }
#pragma unroll
  for (int nd = 0; nd < 4; ++nd)
#pragma unroll
    for (int r = 0; r < 4; ++r)
      atomicAdd(&cbuf[(g * 4 + r) * D_ + nd * 16 + c], cacc[nd][r]);
  __syncthreads();

  if (tid < QBLK) linv[tid] = 1.0f / lsum[tid];
  __syncthreads();

  if (tid < QBLK * D_ / 4) {
    int r = tid >> 4, d0 = (tid & 15) * 4;
    float inv = linv[r];
    float4v cv;
    cv.x = cbuf[r * D_ + d0 + 0] * inv;
    cv.y = cbuf[r * D_ + d0 + 1] * inv;
    cv.z = cbuf[r * D_ + d0 + 2] * inv;
    cv.w = cbuf[r * D_ + d0 + 3] * inv;
    __builtin_nontemporal_store(cv, (float4v*)&outC[((size_t)bh * S_ + q0 + r) * D_ + d0]);
  }

  float* arow = outA + ((size_t)bh * S_ + q0) * (size_t)S_;
#pragma unroll 1
  for (int i = tid; i < QBLK * (S_ / 4); i += NTHREADS) {
    int r = i >> 9, col4 = (i & 511) * 4;
    float inv = linv[r];
    short4v ev = *(const short4v*)&ebuf[r * ESTRIDE + col4];
    float4v av;
    av.x = bf2f(ev[0]) * inv;
    av.y = bf2f(ev[1]) * inv;
    av.z = bf2f(ev[2]) * inv;
    av.w = bf2f(ev[3]) * inv;
    __builtin_nontemporal_store(av, (float4v*)&arow[(size_t)r * S_ + col4]);
  }
}

extern "C" void kernel_launch(void* const* d_in, const int* in_sizes, int n_in,
                              void* d_out, int out_size, void* d_ws, size_t ws_size,
                              hipStream_t stream) {
  const float*   Q     = (const float*)d_in[0];
  const float*   K     = (const float*)d_in[1];
  const float*   V     = (const float*)d_in[2];
  const float*   scale = (const float*)d_in[3];
  const uint8_t* M     = (const uint8_t*)d_in[4];
  uint32_t* flag = (uint32_t*)d_ws;
  float* outC = (float*)d_out;
  float* outA = outC + (size_t)B_ * H_ * S_ * D_;

  hipMemsetAsync(flag, 0, 4, stream);
  detect_mask_dtype<<<dim3(1), dim3(256), 0, stream>>>(M, flag);

  const bool prep = ws_size >= (size_t)64 + KBF_BYTES + VT_BYTES;
  if (prep) {
    short* Kbf = (short*)((char*)d_ws + 64);
    short* VT  = (short*)((char*)d_ws + 64 + KBF_BYTES);
    prep_k<<<dim3((B_ * H_ * S_ * D_) / (256 * 8)), dim3(256), 0, stream>>>(K, Kbf);
    prep_vt<<<dim3(B_ * H_ * (S_ / 64)), dim3(256), 0, stream>>>(V, VT);
    hipFuncSetAttribute(reinterpret_cast<const void*>(attn_fused<1>),
                        hipFuncAttributeMaxDynamicSharedMemorySize, SMEM_BYTES);
    attn_fused<1><<<dim3(B_ * H_ * (S_ / QBLK)), dim3(NTHREADS), SMEM_BYTES, stream>>>(
        Q, K, V, scale, M, flag, Kbf, VT, outC, outA);
  } else {
    hipFuncSetAttribute(reinterpret_cast<const void*>(attn_fused<0>),
                        hipFuncAttributeMaxDynamicSharedMemorySize, SMEM_BYTES);
    attn_fused<0><<<dim3(B_ * H_ * (S_ / QBLK)), dim3(NTHREADS), SMEM_BYTES, stream>>>(
        Q, K, V, scale, M, flag, nullptr, nullptr, outC, outA);
  }
}